// Round 1
// baseline (2296.172 us; speedup 1.0000x reference)
//
#include <hip/hip_runtime.h>

#define N_ACTIVE 200000
#define N_IN 64
#define N_OUT 64
#define K_FILT 27
#define R_PAIRS 100000
#define TP 64  // pairs (rulebook rows) per block

// ---------------------------------------------------------------------------
// out[site][o] = bias[o]  (full overwrite: also clears the 0xAA poison)
// ---------------------------------------------------------------------------
__global__ __launch_bounds__(256) void init_out(const float* __restrict__ bias,
                                                float* __restrict__ out) {
    int t = blockIdx.x * blockDim.x + threadIdx.x;
    int idx = t * 4;
    if (idx >= N_ACTIVE * N_OUT) return;
    int col = idx & (N_OUT - 1);
    float4 b = *reinterpret_cast<const float4*>(&bias[col]);
    *reinterpret_cast<float4*>(&out[idx]) = b;
}

// ---------------------------------------------------------------------------
// One block: filter offset k = blockIdx.y, pairs [r0, r0+64) of the rulebook.
// Stage W[k] (64x64) and gathered features transposed fT[i][p] in LDS,
// compute 64x64 contrib tile with 4x4 register blocking, scatter-atomicAdd.
// ---------------------------------------------------------------------------
__global__ __launch_bounds__(256) void subm_conv(
    const float* __restrict__ feat,     // [N_ACTIVE][64]
    const float* __restrict__ weight,   // [K][64][64] contiguous
    const int* __restrict__ in_idx,     // [K][R]
    const int* __restrict__ out_idx,    // [K][R]
    float* __restrict__ out)            // [N_ACTIVE][64]
{
    __shared__ float Wlds[64][64];   // Wlds[i][o]
    __shared__ float fT[64][64];     // fT[i][p]  (transposed gathered rows)

    const int k  = blockIdx.y;
    const int r0 = blockIdx.x * TP;
    const int t  = threadIdx.x;

    // ---- stage W[k]: 4096 floats, 4 coalesced float4 per thread ----
    {
        const float4* wsrc = reinterpret_cast<const float4*>(weight + k * (64 * 64));
        float4* wdst = reinterpret_cast<float4*>(&Wlds[0][0]);
        #pragma unroll
        for (int j = 0; j < 4; ++j) wdst[j * 256 + t] = wsrc[j * 256 + t];
    }

    // ---- stage gathered rows, transposed: 4 threads per pair ----
    {
        int p = t >> 2;          // pair 0..63
        int q = t & 3;           // quarter of the 64-float row
        int r = r0 + p;
        if (r < R_PAIRS) {
            int in_row = in_idx[k * R_PAIRS + r];
            const float4* fsrc =
                reinterpret_cast<const float4*>(feat + in_row * 64 + q * 16);
            #pragma unroll
            for (int j4 = 0; j4 < 4; ++j4) {
                float4 v = fsrc[j4];
                int e = q * 16 + j4 * 4;
                fT[e + 0][p] = v.x;
                fT[e + 1][p] = v.y;
                fT[e + 2][p] = v.z;
                fT[e + 3][p] = v.w;
            }
        } else {
            #pragma unroll
            for (int j = 0; j < 16; ++j) fT[q * 16 + j][p] = 0.f;
        }
    }
    __syncthreads();

    // ---- compute: wave w owns pairs [w*16, w*16+16); lane = 4x4 sub-tile ----
    const int w    = t >> 6;
    const int lane = t & 63;
    const int pg   = lane >> 4;      // pair group within wave (0..3)
    const int cg   = lane & 15;      // column group (0..15)
    const int pbase = w * 16 + pg * 4;
    const int cbase = cg * 4;

    float acc[4][4] = {{0.f}};
    #pragma unroll 8
    for (int i = 0; i < 64; ++i) {
        float4 wv = *reinterpret_cast<const float4*>(&Wlds[i][cbase]);
        float4 fv = *reinterpret_cast<const float4*>(&fT[i][pbase]);
        float fa[4] = {fv.x, fv.y, fv.z, fv.w};
        float wa[4] = {wv.x, wv.y, wv.z, wv.w};
        #pragma unroll
        for (int pi = 0; pi < 4; ++pi)
            #pragma unroll
            for (int ci = 0; ci < 4; ++ci)
                acc[pi][ci] += fa[pi] * wa[ci];
    }

    // ---- scatter-accumulate ----
    #pragma unroll
    for (int pi = 0; pi < 4; ++pi) {
        int r = r0 + pbase + pi;
        if (r < R_PAIRS) {
            int orow = out_idx[k * R_PAIRS + r];
            float* dst = out + orow * 64 + cbase;
            #pragma unroll
            for (int ci = 0; ci < 4; ++ci) atomicAdd(dst + ci, acc[pi][ci]);
        }
    }
}

extern "C" void kernel_launch(void* const* d_in, const int* in_sizes, int n_in,
                              void* d_out, int out_size, void* d_ws, size_t ws_size,
                              hipStream_t stream) {
    const float* feat   = (const float*)d_in[0];
    const float* weight = (const float*)d_in[1];
    const float* bias   = (const float*)d_in[2];
    const int*   in_idx = (const int*)d_in[3];
    const int*   out_idx= (const int*)d_in[4];
    float* out = (float*)d_out;

    int n_out_elems = N_ACTIVE * N_OUT;
    init_out<<<dim3((n_out_elems / 4 + 255) / 256), dim3(256), 0, stream>>>(bias, out);

    dim3 grid((R_PAIRS + TP - 1) / TP, K_FILT);
    subm_conv<<<grid, dim3(256), 0, stream>>>(feat, weight, in_idx, out_idx, out);
}